// Round 1
// baseline (458.041 us; speedup 1.0000x reference)
//
#include <hip/hip_runtime.h>
#include <hip/hip_bf16.h>
#include <stdint.h>

// Attention_48241072668890: x@Wq^T -> flash-attn over fp32 KV cache -> @Wo^T
// Strategy: skip dead wk/wv projections; bf16 MFMA (tolerance = 2% of max|ref|);
// m97-style 128^2 gemm_bt for both projections; QT=64/KT=64 flash attention with
// XOR-swizzled LDS (pre-swizzled global source so global_load_lds stays linear).

#define DIM   4096
#define NH    32
#define HD    128
#define BB    2
#define SS    1024
#define CC    2048

typedef __bf16 bf16x8 __attribute__((ext_vector_type(8)));
typedef float  f32x4  __attribute__((ext_vector_type(4)));

__device__ __forceinline__ unsigned short f2bf(float f) {
  union { __hip_bfloat16 h; unsigned short u; } cv;
  cv.h = __float2bfloat16(f);
  return cv.u;
}

__device__ __forceinline__ void gl_lds16(const void* g, void* l) {
  __builtin_amdgcn_global_load_lds(
      (__attribute__((address_space(1))) void*)(uintptr_t)(g),
      (__attribute__((address_space(3))) void*)(l), 16, 0, 0);
}

// ---------------- converts ----------------
__global__ void conv_f32_bf16(const float* __restrict__ in, unsigned short* __restrict__ out, int n4) {
  int i = blockIdx.x * blockDim.x + threadIdx.x;
  int stride = gridDim.x * blockDim.x;
  for (; i < n4; i += stride) {
    float4 v = reinterpret_cast<const float4*>(in)[i];
    ushort4 o;
    o.x = f2bf(v.x); o.y = f2bf(v.y); o.z = f2bf(v.z); o.w = f2bf(v.w);
    reinterpret_cast<ushort4*>(out)[i] = o;
  }
}

// cache_k [B,C,NH,HD] f32 -> [B*NH, C, HD] bf16 (head-major gather)
__global__ void conv_k(const float* __restrict__ in, unsigned short* __restrict__ out) {
  const int total4 = BB * NH * CC * HD / 4;
  int i = blockIdx.x * blockDim.x + threadIdx.x;
  int stride = gridDim.x * blockDim.x;
  for (; i < total4; i += stride) {
    size_t o = (size_t)i * 4;
    int d   = (int)(o & (HD - 1));
    size_t r = o >> 7;                 // (b*NH+h)*CC + c
    int c   = (int)(r & (CC - 1));
    int bh  = (int)(r >> 11);
    int hh = bh & (NH - 1), bb = bh >> 5;
    float4 v = *reinterpret_cast<const float4*>(in + ((size_t)(bb * CC + c) * NH + hh) * HD + d);
    ushort4 u; u.x = f2bf(v.x); u.y = f2bf(v.y); u.z = f2bf(v.z); u.w = f2bf(v.w);
    *reinterpret_cast<ushort4*>(out + o) = u;
  }
}

// cache_v [B,C,NH,HD] f32 -> [B*NH, HD, C] bf16 (transposed per head, LDS tile)
__global__ void conv_v_t(const float* __restrict__ in, unsigned short* __restrict__ out) {
  __shared__ float tile[32][33];
  const int c0 = blockIdx.x * 32, d0 = blockIdx.y * 32;
  const int bh = blockIdx.z;
  const int hh = bh & (NH - 1), bb = bh >> 5;
  const int tx = threadIdx.x, ty = threadIdx.y;   // 32 x 8
#pragma unroll
  for (int i = 0; i < 4; ++i) {
    int c = c0 + ty + i * 8;
    tile[ty + i * 8][tx] = in[((size_t)(bb * CC + c) * NH + hh) * HD + d0 + tx];
  }
  __syncthreads();
#pragma unroll
  for (int i = 0; i < 4; ++i) {
    int d = d0 + ty + i * 8;
    out[((size_t)bh * HD + d) * CC + c0 + tx] = f2bf(tile[tx][ty + i * 8]);
  }
}

// ---------------- GEMM: C[M,N] = A[M,K] * B[N,K]^T  (m97 structure) ----------------
template <int OUT_BF16>
__global__ __launch_bounds__(256, 2) void gemm_bt(
    const unsigned short* __restrict__ A,
    const unsigned short* __restrict__ Bw,
    void* __restrict__ Cout,
    int M, int N, int K, float scale)
{
  __shared__ __align__(16) unsigned short As[128 * 32];
  __shared__ __align__(16) unsigned short Bs[128 * 32];
  const int t = threadIdx.x;
  const int w = t >> 6, lane = t & 63;
  const int wr = w >> 1, wc = w & 1;
  const int bm0 = blockIdx.y * 128, bn0 = blockIdx.x * 128;

  const unsigned short* aSrc = A  + (size_t)(bm0 + (t >> 2)) * K + (t & 3) * 8;
  const unsigned short* bSrc = Bw + (size_t)(bn0 + (t >> 2)) * K + (t & 3) * 8;
  char* aDst = (char*)As + w * 1024;
  char* bDst = (char*)Bs + w * 1024;
  const size_t half = (size_t)64 * K;

  f32x4 acc[4][4];
#pragma unroll
  for (int m = 0; m < 4; ++m)
#pragma unroll
    for (int n = 0; n < 4; ++n) acc[m][n] = (f32x4){0.f, 0.f, 0.f, 0.f};

  for (int k0 = 0; k0 < K; k0 += 32) {
    gl_lds16(aSrc,        aDst);
    gl_lds16(aSrc + half, aDst + 4096);
    gl_lds16(bSrc,        bDst);
    gl_lds16(bSrc + half, bDst + 4096);
    aSrc += 32; bSrc += 32;
    __syncthreads();

    bf16x8 af[4], bf[4];
#pragma unroll
    for (int m = 0; m < 4; ++m)
      af[m] = *(const bf16x8*)&As[(wr * 64 + m * 16 + (lane & 15)) * 32 + (lane >> 4) * 8];
#pragma unroll
    for (int n = 0; n < 4; ++n)
      bf[n] = *(const bf16x8*)&Bs[(wc * 64 + n * 16 + (lane & 15)) * 32 + (lane >> 4) * 8];
#pragma unroll
    for (int m = 0; m < 4; ++m)
#pragma unroll
      for (int n = 0; n < 4; ++n)
        acc[m][n] = __builtin_amdgcn_mfma_f32_16x16x32_bf16(af[m], bf[n], acc[m][n], 0, 0, 0);
    __syncthreads();
  }

  const int r0 = (lane >> 4) * 4, cl = lane & 15;
#pragma unroll
  for (int m = 0; m < 4; ++m) {
#pragma unroll
    for (int n = 0; n < 4; ++n) {
      int row = bm0 + wr * 64 + m * 16 + r0;
      int col = bn0 + wc * 64 + n * 16 + cl;
#pragma unroll
      for (int r = 0; r < 4; ++r) {
        float v = acc[m][n][r] * scale;
        if (OUT_BF16) ((unsigned short*)Cout)[(size_t)(row + r) * N + col] = f2bf(v);
        else          ((float*)Cout)[(size_t)(row + r) * N + col] = v;
      }
    }
  }
}

// ---------------- flash attention ----------------
// Q [B,S,DIM] bf16 (1/sqrt(hd) folded), K [B*NH,C,HD] bf16, Vt [B*NH,HD,C] bf16,
// mask [S,C] f32, out [B,S,DIM] bf16. QT=64 (4 waves x 16 rows), KT=64.
__global__ __launch_bounds__(256, 2) void attn_fwd(
    const unsigned short* __restrict__ Qb,
    const unsigned short* __restrict__ Kb,
    const unsigned short* __restrict__ Vtb,
    const float* __restrict__ mask,
    unsigned short* __restrict__ Ob)
{
  __shared__ __align__(16) unsigned short Qs[64 * 128];
  __shared__ __align__(16) unsigned short Ks[64 * 128];
  __shared__ __align__(16) unsigned short Vs[128 * 64];
  __shared__ __align__(16) unsigned short Ps[4][16 * 64];

  const int t = threadIdx.x, w = t >> 6, lane = t & 63;
  const int bid = blockIdx.x;
  const int qt = bid & 15, bh = bid >> 4;
  const int hh = bh & (NH - 1), bb = bh >> 5;
  const int q0 = qt * 64;

  // stage Q once (source pre-swizzled: LDS chunk (row,cc) holds global chunk cc^(row&7))
  {
    const unsigned short* src = Qb + ((size_t)(bb * SS + q0 + (t >> 4))) * DIM + hh * HD
                                + (((t & 15) ^ ((t >> 4) & 7)) * 8);
    char* dst = (char*)Qs + w * 1024;
#pragma unroll
    for (int i = 0; i < 4; ++i)
      gl_lds16(src + (size_t)i * 16 * DIM, dst + i * 4096);
  }

  const unsigned short* kSrc = Kb + ((size_t)bh * CC + (t >> 4)) * HD
                               + (((t & 15) ^ ((t >> 4) & 7)) * 8);
  const unsigned short* vSrc = Vtb + ((size_t)bh * HD + (t >> 3)) * CC
                               + (((t & 7) ^ ((t >> 3) & 7)) * 8);

  f32x4 acc_o[8];
#pragma unroll
  for (int i = 0; i < 8; ++i) acc_o[i] = (f32x4){0.f, 0.f, 0.f, 0.f};
  float m_run[4], l_run[4];
#pragma unroll
  for (int r = 0; r < 4; ++r) { m_run[r] = -1e30f; l_run[r] = 0.f; }

  const int swz = (lane & 7) << 3;        // row&7 == lane&7 for all frag-read rows
  const int rb4 = (lane >> 4) * 4;
  const float LOG2E = 1.4426950408889634f;

  for (int c0 = 0; c0 < CC; c0 += 64) {
    {
      char* kd = (char*)Ks + w * 1024;
      char* vd = (char*)Vs + w * 1024;
#pragma unroll
      for (int i = 0; i < 4; ++i) {
        gl_lds16(kSrc + (size_t)(c0 + i * 16) * HD, kd + i * 4096);
        gl_lds16(vSrc + (size_t)i * 32 * CC + c0,   vd + i * 4096);
      }
    }
    __syncthreads();

    // QK^T: this wave's 16 q-rows x 64 c-cols
    f32x4 sc[4];
#pragma unroll
    for (int nf = 0; nf < 4; ++nf) sc[nf] = (f32x4){0.f, 0.f, 0.f, 0.f};
#pragma unroll
    for (int kk = 0; kk < 4; ++kk) {
      bf16x8 qf = *(const bf16x8*)&Qs[((w * 16 + (lane & 15)) * 128 + kk * 32 + (lane >> 4) * 8) ^ swz];
#pragma unroll
      for (int nf = 0; nf < 4; ++nf) {
        bf16x8 kf = *(const bf16x8*)&Ks[((nf * 16 + (lane & 15)) * 128 + kk * 32 + (lane >> 4) * 8) ^ swz];
        sc[nf] = __builtin_amdgcn_mfma_f32_16x16x32_bf16(qf, kf, sc[nf], 0, 0, 0);
      }
    }

    // + mask (fp32 loads, coalesced per 16-lane group)
#pragma unroll
    for (int nf = 0; nf < 4; ++nf)
#pragma unroll
      for (int r = 0; r < 4; ++r)
        sc[nf][r] += mask[(size_t)(q0 + w * 16 + rb4 + r) * CC + c0 + nf * 16 + (lane & 15)];

    // online softmax (wave-parallel: 16-lane xor-shuffle row reduce)
    float mx[4];
#pragma unroll
    for (int r = 0; r < 4; ++r)
      mx[r] = fmaxf(fmaxf(sc[0][r], sc[1][r]), fmaxf(sc[2][r], sc[3][r]));
#pragma unroll
    for (int d = 1; d < 16; d <<= 1)
#pragma unroll
      for (int r = 0; r < 4; ++r)
        mx[r] = fmaxf(mx[r], __shfl_xor(mx[r], d));

    float corr[4], ls[4];
#pragma unroll
    for (int r = 0; r < 4; ++r) {
      float mn = fmaxf(m_run[r], mx[r]);
      corr[r] = exp2f((m_run[r] - mn) * LOG2E);
      m_run[r] = mn;
      ls[r] = 0.f;
    }
#pragma unroll
    for (int nf = 0; nf < 4; ++nf)
#pragma unroll
      for (int r = 0; r < 4; ++r) {
        float p = exp2f((sc[nf][r] - m_run[r]) * LOG2E);
        sc[nf][r] = p; ls[r] += p;
      }
#pragma unroll
    for (int d = 1; d < 16; d <<= 1)
#pragma unroll
      for (int r = 0; r < 4; ++r)
        ls[r] += __shfl_xor(ls[r], d);
#pragma unroll
    for (int r = 0; r < 4; ++r) l_run[r] = l_run[r] * corr[r] + ls[r];
#pragma unroll
    for (int nd = 0; nd < 8; ++nd)
#pragma unroll
      for (int r = 0; r < 4; ++r) acc_o[nd][r] *= corr[r];

    // P -> LDS bf16 (swizzled write, per-wave private buffer)
#pragma unroll
    for (int r = 0; r < 4; ++r) {
      int rw = rb4 + r;
      int rsw = (rw & 7) << 3;
#pragma unroll
      for (int nf = 0; nf < 4; ++nf)
        Ps[w][rw * 64 + ((nf * 16 + (lane & 15)) ^ rsw)] = f2bf(sc[nf][r]);
    }

    // PV: acc_o[nd] += P[16x64] * V[64 x 128]
#pragma unroll
    for (int kk = 0; kk < 2; ++kk) {
      bf16x8 pf = *(const bf16x8*)&Ps[w][((lane & 15) * 64 + kk * 32 + (lane >> 4) * 8) ^ swz];
#pragma unroll
      for (int nd = 0; nd < 8; ++nd) {
        bf16x8 vf = *(const bf16x8*)&Vs[((nd * 16 + (lane & 15)) * 64 + kk * 32 + (lane >> 4) * 8) ^ swz];
        acc_o[nd] = __builtin_amdgcn_mfma_f32_16x16x32_bf16(pf, vf, acc_o[nd], 0, 0, 0);
      }
    }
    __syncthreads();
  }

  // epilogue: O / l
#pragma unroll
  for (int nd = 0; nd < 8; ++nd)
#pragma unroll
    for (int r = 0; r < 4; ++r) {
      float v = acc_o[nd][r] / l_run[r];
      int row = q0 + w * 16 + rb4 + r;
      Ob[(size_t)(bb * SS + row) * DIM + hh * HD + nd * 16 + (lane & 15)] = f2bf(v);
    }
}

// ---------------- launch ----------------
extern "C" void kernel_launch(void* const* d_in, const int* in_sizes, int n_in,
                              void* d_out, int out_size, void* d_ws, size_t ws_size,
                              hipStream_t stream) {
  const float* x       = (const float*)d_in[0];
  const float* mask    = (const float*)d_in[2];   // [1,1,S,C]
  const float* cache_k = (const float*)d_in[4];   // [B,C,NH,HD]
  const float* cache_v = (const float*)d_in[5];
  const float* wq      = (const float*)d_in[6];   // [DIM,DIM]
  const float* wo      = (const float*)d_in[9];
  float* out = (float*)d_out;

  // workspace layout (needs 128 MiB):
  char* ws = (char*)d_ws;
  unsigned short* Wbf  = (unsigned short*)(ws);                                  // 32 MiB (wq, later wo)
  unsigned short* xbf  = (unsigned short*)(ws + 33554432);                       // 16 MiB (x, later attn-out)
  unsigned short* qbf  = (unsigned short*)(ws + 33554432 + 16777216);            // 16 MiB
  unsigned short* kbf  = (unsigned short*)(ws + 33554432 + 2 * 16777216);        // 32 MiB
  unsigned short* vtbf = (unsigned short*)(ws + 2 * 33554432 + 2 * 16777216);    // 32 MiB

  conv_f32_bf16<<<2048, 256, 0, stream>>>(x,  xbf, BB * SS * DIM / 4);
  conv_f32_bf16<<<2048, 256, 0, stream>>>(wq, Wbf, DIM * DIM / 4);
  dim3 gg(DIM / 128, (BB * SS) / 128);
  gemm_bt<1><<<gg, 256, 0, stream>>>(xbf, Wbf, qbf, BB * SS, DIM, DIM, 0.08838834764831843f);
  conv_k<<<2048, 256, 0, stream>>>(cache_k, kbf);
  conv_v_t<<<dim3(CC / 32, HD / 32, BB * NH), dim3(32, 8, 1), 0, stream>>>(cache_v, vtbf);
  attn_fwd<<<BB * NH * 16, 256, 0, stream>>>(qbf, kbf, vtbf, mask, xbf);
  conv_f32_bf16<<<2048, 256, 0, stream>>>(wo, Wbf, DIM * DIM / 4);
  gemm_bt<0><<<gg, 256, 0, stream>>>(xbf, Wbf, out, BB * SS, DIM, DIM, 1.0f);
}